// Round 7
// baseline (151.820 us; speedup 1.0000x reference)
//
#include <hip/hip_runtime.h>
#include <stdint.h>

typedef float  float4v  __attribute__((ext_vector_type(4)));
typedef long long llong2v __attribute__((ext_vector_type(2)));
typedef unsigned int uint4v __attribute__((ext_vector_type(4)));

// Problem constants (N=8192, n_in=256, m=256, k=8)
// GEMM: [8192 x 512] x [512 x 8192] in fp8 e4m3 with fused LSTM epilogue.
// W pre-scaled by 16 (e4m3 normal range); acc scaled by 1/16 in epilogue.
// A/Bt stored as [panel][kt][row 256][64B] so staging is fully contiguous:
// one gll16 wave-op = 1KB sequential (was 16 x 64B scattered at 512B stride).

__device__ __forceinline__ unsigned int pk4fp8(float a, float b, float c, float d) {
  unsigned int p = (unsigned int)__builtin_amdgcn_cvt_pk_fp8_f32(a, b, 0, false);
  p = (unsigned int)__builtin_amdgcn_cvt_pk_fp8_f32(c, d, (int)p, true);
  return p;
}

__device__ __forceinline__ float sigm(float x) {
  return __builtin_amdgcn_rcpf(1.0f + __expf(-x));
}
__device__ __forceinline__ float tanh_(float x) {
  return fmaf(2.0f, __builtin_amdgcn_rcpf(1.0f + __expf(-2.0f * x)), -1.0f);
}

__device__ __forceinline__ void gll16(const void* g, void* l) {
  __builtin_amdgcn_global_load_lds((const __attribute__((address_space(1))) void*)g,
                                   (__attribute__((address_space(3))) void*)l, 16, 0, 0);
}

#define BARRIER   asm volatile("s_barrier" ::: "memory")
#define WAITLGKM  asm volatile("s_waitcnt lgkmcnt(0)" ::: "memory")
#define WAITVM4   asm volatile("s_waitcnt vmcnt(4)" ::: "memory")
#define WAITVM0   asm volatile("s_waitcnt vmcnt(0)" ::: "memory")
#define PRIO1     __builtin_amdgcn_s_setprio(1)
#define PRIO0     __builtin_amdgcn_s_setprio(0)

// ------------- P1+L fused: A = [rb][kt][row][64B] fp8 K-permuted + logits ---------
__global__ void prep_logits(const float* __restrict__ x, const float* __restrict__ h,
                            const float* __restrict__ u, const float* __restrict__ Wxz,
                            const float* __restrict__ Whz, const float* __restrict__ bxz,
                            const void* __restrict__ taup,
                            uint8_t* __restrict__ A,
                            float* __restrict__ z_out, float* __restrict__ qz_out) {
  int lane = threadIdx.x & 63;
  int n = blockIdx.x * 4 + (threadIdx.x >> 6);
  float4v xv = *(const float4v*)(x + (size_t)n * 256 + lane * 4);
  float4v hv = *(const float4v*)(h + (size_t)n * 256 + lane * 4);

  // fp8 A write: lane i covers orig k = 4i..4i+3 (x) and 256+4i.. (h).
  // within-kt offset o (K-granule permutation), kt = lane>>4 (x) / 4+(lane>>4) (h)
  {
    unsigned int px = pk4fp8(xv[0], xv[1], xv[2], xv[3]);
    unsigned int ph = pk4fp8(hv[0], hv[1], hv[2], hv[3]);
    int o = (((lane >> 1) & 3) << 4) + (((lane >> 3) & 1) << 3) + ((lane & 1) << 2);
    uint8_t* base = A + (size_t)(n >> 8) * 131072 + (n & 255) * 64 + o;
    int ktx = lane >> 4;
    *(unsigned int*)(base + ktx * 16384) = px;
    *(unsigned int*)(base + (4 + ktx) * 16384) = ph;
  }

  // ---- logits
  float p[8];
#pragma unroll
  for (int j = 0; j < 8; ++j) p[j] = 0.0f;
#pragma unroll
  for (int ii = 0; ii < 4; ++ii) {
    int i = lane * 4 + ii;
    float xs = xv[ii], hs = hv[ii];
#pragma unroll
    for (int j = 0; j < 8; ++j)
      p[j] += xs * Wxz[i * 8 + j] + hs * Whz[i * 8 + j];
  }
#pragma unroll
  for (int j = 0; j < 8; ++j)
    for (int off = 32; off > 0; off >>= 1) p[j] += __shfl_down(p[j], off, 64);

  if (lane == 0) {
    int   iv = ((const int*)taup)[0];
    float fv = ((const float*)taup)[0];
    float tau = (iv >= 1 && iv < 100000) ? (float)iv : fv;
    float tinv = 1.0f / tau;

    float logit[8], e[8];
    float mx = -1e30f;
#pragma unroll
    for (int j = 0; j < 8; ++j) { logit[j] = p[j] + bxz[j]; mx = fmaxf(mx, logit[j]); }
    float s = 0.0f;
#pragma unroll
    for (int j = 0; j < 8; ++j) { e[j] = __expf(logit[j] - mx); s += e[j]; }
    float inv = 1.0f / s;
#pragma unroll
    for (int j = 0; j < 8; ++j) qz_out[(size_t)n * 8 + j] = e[j] * inv;

    float t[8];
    float mt = -1e30f;
#pragma unroll
    for (int j = 0; j < 8; ++j) {
      float uu = u[(size_t)n * 8 + j];
      float g = -__logf(-__logf(uu + 1e-10f) + 1e-10f);
      t[j] = (logit[j] + g) * tinv;
      mt = fmaxf(mt, t[j]);
    }
    float s2 = 0.0f;
#pragma unroll
    for (int j = 0; j < 8; ++j) { e[j] = __expf(t[j] - mt); s2 += e[j]; }
    float inv2 = 1.0f / s2;
#pragma unroll
    for (int j = 0; j < 8; ++j) z_out[(size_t)n * 8 + j] = e[j] * inv2;
  }
}

// ---------------- P2: Bt = [cb][kt][row][64B] fp8, col+K-permuted -----------------
// p(C) = (mm>>3)*256 + (g>>1)*128 + (g&1)*64 + (kk>>1)*16 + (kk&1)*8 + (mm&7)
__global__ void prep_Bt(const float* __restrict__ Wx, const float* __restrict__ Wh,
                        uint8_t* __restrict__ Bt) {
  __shared__ float tile[64][64];
  int tid = threadIdx.x;
  int wi = blockIdx.x & 7;            // 64-k window == kt
  int C0 = (blockIdx.x >> 3) << 6;    // 64-col group
#pragma unroll
  for (int qq = 0; qq < 16; ++qq) {
    int flat = qq * 256 + tid;
    int r = flat >> 6, c = flat & 63;
    int ig = wi * 64 + r;
    float v = (ig < 256) ? Wx[(size_t)ig * 8192 + C0 + c]
                         : Wh[(size_t)(ig - 256) * 8192 + C0 + c];
    tile[r][c] = v * 16.0f;
  }
  __syncthreads();
  int c = tid & 63, q = tid >> 6;
  int C = C0 + c;
  int g = C >> 11, kk = (C >> 8) & 7, mm = C & 255;
  int p = ((mm >> 3) << 8) | ((g >> 1) << 7) | ((g & 1) << 6)
        | ((kk >> 1) << 4) | ((kk & 1) << 3) | (mm & 7);
  uint4v o;
  o[0] = pk4fp8(tile[q * 8 + 0][c], tile[q * 8 + 1][c], tile[q * 8 + 2][c], tile[q * 8 + 3][c]);
  o[1] = pk4fp8(tile[q * 8 + 4][c], tile[q * 8 + 5][c], tile[q * 8 + 6][c], tile[q * 8 + 7][c]);
  o[2] = pk4fp8(tile[32 + q * 8 + 0][c], tile[32 + q * 8 + 1][c], tile[32 + q * 8 + 2][c], tile[32 + q * 8 + 3][c]);
  o[3] = pk4fp8(tile[32 + q * 8 + 4][c], tile[32 + q * 8 + 5][c], tile[32 + q * 8 + 6][c], tile[32 + q * 8 + 7][c]);
  *(uint4v*)(Bt + (size_t)(p >> 8) * 131072 + wi * 16384 + (p & 255) * 64 + q * 16) = o;
}

// ---------------- G: fp8 256x256-tile GEMM + fused LSTM epilogue ------------------
// MODE 0 = full; MODE 1 = no-epilogue (acc->scratch); MODE 2 = MODE1 + no staging.
// 8 waves = 2M x 4N. Rows: ha*128 + j*32 + wm*16 + gl*4 + r ; cols: hb*128 + n2*64 + wn*16 + ml
// gate g = hb*2+n2 ; kk = wn*2+(ml>>3) ; mml = ml&7
template <int MODE>
__global__ __launch_bounds__(512, 2) void gates_kernel(
    const uint8_t* __restrict__ A,    // [rb][kt][256][64B] fp8
    const uint8_t* __restrict__ Bt,   // [cb][kt][256][64B] fp8
    const float* __restrict__ c0g,    // [8192][256]
    const float* __restrict__ bias,   // [8192]
    const float* __restrict__ zg,     // [8192][8]
    float* __restrict__ h_out, float* __restrict__ c_out,
    float* __restrict__ scratch) {
  __shared__ char smem[65536];  // A: 2 x 16KB @0 ; B: 2 x 16KB @32768

  const int tid = threadIdx.x;
  const int lane = tid & 63, ml = lane & 15, gl = lane >> 4;
  const int wid = tid >> 6, wm = wid >> 2, wn = wid & 3;

  // XCD-stripe grid mapping (verified R3): xcd owns rb {4x..4x+3}, cb outer
  const int xcd = blockIdx.x & 7;
  const int j_  = blockIdx.x >> 3;
  const int cb  = j_ >> 2;
  const int rb  = (xcd << 2) | (j_ & 3);
  const int row0 = rb << 8;

  const uint8_t* Abp = A + (size_t)rb * 131072;
  const uint8_t* Bbp = Bt + (size_t)cb * 131072;

  // fragment LDS bases (contiguous 1KB per 16-row group: conflict-free)
  const char* pa = smem + ((wm << 4) + ml) * 64 + (gl << 4);
  const char* pb = smem + 32768 + ((wn << 4) + ml) * 64 + (gl << 4);

  // fully linear staging: src [kt][row][64B] -> LDS slot identical image
#define STGF(KTS) do { \
    const int kb_ = (KTS) & 1; \
    const uint8_t* sa_ = Abp + ((KTS) & 7) * 16384 + (tid << 4); \
    const uint8_t* sb_ = Bbp + ((KTS) & 7) * 16384 + (tid << 4); \
    char* da_ = smem + kb_ * 16384 + (tid << 4); \
    char* db_ = smem + 32768 + kb_ * 16384 + (tid << 4); \
    gll16(sa_, da_); gll16(sa_ + 8192, da_ + 8192); \
    gll16(sb_, db_); gll16(sb_ + 8192, db_ + 8192); \
  } while (0)

#define RDA(KB, HF) { _Pragma("unroll") for (int j = 0; j < 4; ++j) \
    af[j] = *(const llong2v*)(pa + (KB) * 16384 + (HF) * 8192 + j * 2048); }
#define RDB(KB, HF, BF) { _Pragma("unroll") for (int n2 = 0; n2 < 2; ++n2) \
    BF[n2] = *(const llong2v*)(pb + (KB) * 16384 + (HF) * 8192 + n2 * 4096); }
#define MM16(AH, BH, BF) { _Pragma("unroll") for (int j = 0; j < 4; ++j) \
    _Pragma("unroll") for (int n2 = 0; n2 < 2; ++n2) { \
      acc[AH][BH][j][n2] = __builtin_amdgcn_mfma_f32_16x16x32_fp8_fp8(af[j][0], BF[n2][0], acc[AH][BH][j][n2], 0, 0, 0); \
      acc[AH][BH][j][n2] = __builtin_amdgcn_mfma_f32_16x16x32_fp8_fp8(af[j][1], BF[n2][1], acc[AH][BH][j][n2], 0, 0, 0); } }

  float4v acc[2][2][4][2];   // [ha][hb][j][n2]
#pragma unroll
  for (int a = 0; a < 2; ++a)
#pragma unroll
    for (int b = 0; b < 2; ++b)
#pragma unroll
      for (int j = 0; j < 4; ++j)
#pragma unroll
        for (int c = 0; c < 2; ++c)
#pragma unroll
          for (int r = 0; r < 4; ++r) acc[a][b][j][c][r] = 0.0f;

  llong2v af[4];
  llong2v bf0[2], bf1[2];

  // prologue: stage kt0 + kt1 (8 loads)
  STGF(0); STGF(1);
  if constexpr (MODE == 2) { WAITVM0; } else { WAITVM4; }
  BARRIER;

#pragma unroll
  for (int kt = 0; kt < 8; ++kt) {
    const int kb = kt & 1;

    RDA(kb, 0); RDB(kb, 0, bf0); RDB(kb, 1, bf1);   // 8 reads
    WAITLGKM;
    PRIO1; MM16(0, 0, bf0); MM16(0, 1, bf1); PRIO0;
    RDA(kb, 1);                                      // 4 reads
    WAITLGKM;
    PRIO1; MM16(1, 1, bf1); MM16(1, 0, bf0); PRIO0;

    BARRIER;                       // all waves' reads of slot kb complete
    if (kt <= 5) {
      if constexpr (MODE != 2) { STGF(kt + 2); WAITVM4; }
      BARRIER;
    } else if (kt == 6) {
      if constexpr (MODE != 2) { WAITVM0; }
      BARRIER;
    }
  }
#undef STGF
#undef RDA
#undef RDB
#undef MM16

  if constexpr (MODE != 0) {
    // keep the whole GEMM live; per-dispatch dur_us read from rocprof
    float s = 0.0f;
#pragma unroll
    for (int a = 0; a < 2; ++a)
#pragma unroll
      for (int b = 0; b < 2; ++b)
#pragma unroll
        for (int j = 0; j < 4; ++j)
#pragma unroll
          for (int c = 0; c < 2; ++c)
#pragma unroll
            for (int r = 0; r < 4; ++r) s += acc[a][b][j][c][r];
    scratch[(size_t)blockIdx.x * 512 + tid] = s;
    return;
  }

  // ---------------- fused LSTM epilogue ----------------
  const int kkl = (wn << 1) | (ml >> 3);
  const int mml = ml & 15 & 7;
  {
    const int mmg = (cb << 3) + mml;
    const float bI = bias[0 * 2048 + kkl * 256 + mmg];
    const float bG = bias[1 * 2048 + kkl * 256 + mmg];
    const float bF = bias[2 * 2048 + kkl * 256 + mmg];
    const float bO = bias[3 * 2048 + kkl * 256 + mmg];
    const float s16 = 0.0625f;   // undo W*16 pre-scale

    float hpart[2][4][4], cpart[2][4][4];
#pragma unroll
    for (int ha = 0; ha < 2; ++ha) {
#pragma unroll
      for (int j = 0; j < 4; ++j) {
        const int nb = row0 + ha * 128 + j * 32 + wm * 16 + gl * 4;
        // gates in-register: I=acc[ha][0][j][0], G=[0][1], F=[1][0], O=[1][1]
#pragma unroll
        for (int r = 0; r < 4; ++r) {
          const int nrow = nb + r;
          float I = fmaf(acc[ha][0][j][0][r], s16, bI);
          float G = fmaf(acc[ha][0][j][1][r], s16, bG);
          float F = fmaf(acc[ha][1][j][0][r], s16, bF);
          float O = fmaf(acc[ha][1][j][1][r], s16, bO);
          float c0v = c0g[(size_t)nrow * 256 + mmg];
          float ct = fmaf(sigm(F), c0v, sigm(I) * tanh_(G));
          float ht = sigm(O) * tanh_(ct);
          float zv = zg[(size_t)nrow * 8 + kkl];
          float h1 = zv * ht, c1 = zv * ct;
          h1 += __shfl_xor(h1, 8, 64);    // combine the wave's 2 kk
          c1 += __shfl_xor(c1, 8, 64);
          hpart[ha][j][r] = h1;
          cpart[ha][j][r] = c1;
        }
      }
    }

    float* pbuf = (float*)smem;   // [wn][256][9] floats = 36KB
    const bool wr = ((ml & 8) == 0);
    // ---- pass 1: h
    if (wr) {
#pragma unroll
      for (int ha = 0; ha < 2; ++ha)
#pragma unroll
        for (int j = 0; j < 4; ++j)
#pragma unroll
          for (int r = 0; r < 4; ++r) {
            int rloc = ha * 128 + j * 32 + wm * 16 + gl * 4 + r;
            pbuf[wn * 2304 + rloc * 9 + mml] = hpart[ha][j][r];
          }
    }
    WAITLGKM; BARRIER;
#pragma unroll
    for (int i = 0; i < 4; ++i) {
      int idx = (i << 9) + tid;
      int rloc = idx >> 3, mm2 = idx & 7;
      float v = pbuf[rloc * 9 + mm2] + pbuf[2304 + rloc * 9 + mm2]
              + pbuf[4608 + rloc * 9 + mm2] + pbuf[6912 + rloc * 9 + mm2];
      h_out[(size_t)(row0 + rloc) * 256 + (cb << 3) + mm2] = v;
    }
    WAITLGKM; BARRIER;
    // ---- pass 2: c
    if (wr) {
#pragma unroll
      for (int ha = 0; ha < 2; ++ha)
#pragma unroll
        for (int j = 0; j < 4; ++j)
#pragma unroll
          for (int r = 0; r < 4; ++r) {
            int rloc = ha * 128 + j * 32 + wm * 16 + gl * 4 + r;
            pbuf[wn * 2304 + rloc * 9 + mml] = cpart[ha][j][r];
          }
    }
    WAITLGKM; BARRIER;
#pragma unroll
    for (int i = 0; i < 4; ++i) {
      int idx = (i << 9) + tid;
      int rloc = idx >> 3, mm2 = idx & 7;
      float v = pbuf[rloc * 9 + mm2] + pbuf[2304 + rloc * 9 + mm2]
              + pbuf[4608 + rloc * 9 + mm2] + pbuf[6912 + rloc * 9 + mm2];
      c_out[(size_t)(row0 + rloc) * 256 + (cb << 3) + mm2] = v;
    }
  }
}

extern "C" void kernel_launch(void* const* d_in, const int* in_sizes, int n_in,
                              void* d_out, int out_size, void* d_ws, size_t ws_size,
                              hipStream_t stream) {
  const float* x   = (const float*)d_in[0];
  const float* h0  = (const float*)d_in[1];
  const float* c0  = (const float*)d_in[2];
  const float* u   = (const float*)d_in[3];
  const float* Wxz = (const float*)d_in[4];
  const float* Whz = (const float*)d_in[5];
  const float* Wx4 = (const float*)d_in[6];
  const float* Wh4 = (const float*)d_in[7];
  const float* bxz = (const float*)d_in[8];
  const float* b4  = (const float*)d_in[9];
  const void*  tau = d_in[10];

  float* out    = (float*)d_out;
  float* z_out  = out;                       // [8192][8]
  float* qz_out = out + 65536;               // [8192][8]
  float* h_out  = out + 131072;              // [8192][256]
  float* c_out  = out + 131072 + 2097152;    // [8192][256]

  uint8_t* A  = (uint8_t*)d_ws;              // 4MB fp8
  uint8_t* Bt = A + 4194304;                 // 4MB fp8
  float* scratch = (float*)((uint8_t*)d_ws + 12 * 1024 * 1024);  // ablation sink

  prep_logits<<<2048, 256, 0, stream>>>(x, h0, u, Wxz, Whz, bxz, tau, A, z_out, qz_out);
  prep_Bt<<<1024, 256, 0, stream>>>(Wx4, Wh4, Bt);
  gates_kernel<0><<<1024, 512, 0, stream>>>(A, Bt, c0, b4, z_out, h_out, c_out, scratch);
  // ---- ablation dispatches (diagnostic; write scratch only, removed next round)
  gates_kernel<1><<<512, 512, 0, stream>>>(A, Bt, c0, b4, z_out, h_out, c_out, scratch);
  gates_kernel<2><<<512, 512, 0, stream>>>(A, Bt, c0, b4, z_out, h_out, c_out, scratch);
}

// Round 8
// 89.885 us; speedup vs baseline: 1.6890x; 1.6890x over previous
//
#include <hip/hip_runtime.h>
#include <stdint.h>

typedef float  float4v  __attribute__((ext_vector_type(4)));
typedef long long llong2v __attribute__((ext_vector_type(2)));
typedef unsigned int uint4v __attribute__((ext_vector_type(4)));

// Problem constants (N=8192, n_in=256, m=256, k=8)
// GEMM: [8192 x 512] x [512 x 8192] fp8 e4m3, fused LSTM epilogue.
// W pre-scaled by 16; acc scaled by 1/16 in epilogue.
// A  layout: [rb 64][kt 8][128 rows][64B]   (64KB panels, staging fully linear)
// Bt layout: [cb 32][kt 8][256 p][64B]      (128KB panels)
// Tile 128x256, 8 waves = 2M x 4N, acc 64 f32/lane -> 2 blocks/CU resident.

__device__ __forceinline__ unsigned int pk4fp8(float a, float b, float c, float d) {
  unsigned int p = (unsigned int)__builtin_amdgcn_cvt_pk_fp8_f32(a, b, 0, false);
  p = (unsigned int)__builtin_amdgcn_cvt_pk_fp8_f32(c, d, (int)p, true);
  return p;
}

__device__ __forceinline__ float sigm(float x) {
  return __builtin_amdgcn_rcpf(1.0f + __expf(-x));
}
__device__ __forceinline__ float tanh_(float x) {
  return fmaf(2.0f, __builtin_amdgcn_rcpf(1.0f + __expf(-2.0f * x)), -1.0f);
}

__device__ __forceinline__ void gll16(const void* g, void* l) {
  __builtin_amdgcn_global_load_lds((const __attribute__((address_space(1))) void*)g,
                                   (__attribute__((address_space(3))) void*)l, 16, 0, 0);
}

#define BARRIER   asm volatile("s_barrier" ::: "memory")
#define WAITLGKM  asm volatile("s_waitcnt lgkmcnt(0)" ::: "memory")
#define WAITVM3   asm volatile("s_waitcnt vmcnt(3)" ::: "memory")
#define WAITVM0   asm volatile("s_waitcnt vmcnt(0)" ::: "memory")
#define PRIO1     __builtin_amdgcn_s_setprio(1)
#define PRIO0     __builtin_amdgcn_s_setprio(0)

// ------------- P1+L fused: A = [rb][kt][row][64B] fp8 K-permuted + logits ---------
__global__ void prep_logits(const float* __restrict__ x, const float* __restrict__ h,
                            const float* __restrict__ u, const float* __restrict__ Wxz,
                            const float* __restrict__ Whz, const float* __restrict__ bxz,
                            const void* __restrict__ taup,
                            uint8_t* __restrict__ A,
                            float* __restrict__ z_out, float* __restrict__ qz_out) {
  int lane = threadIdx.x & 63;
  int n = blockIdx.x * 4 + (threadIdx.x >> 6);
  float4v xv = *(const float4v*)(x + (size_t)n * 256 + lane * 4);
  float4v hv = *(const float4v*)(h + (size_t)n * 256 + lane * 4);

  // fp8 A write: lane i covers orig k = 4i..4i+3 (x) and 256+4i.. (h).
  {
    unsigned int px = pk4fp8(xv[0], xv[1], xv[2], xv[3]);
    unsigned int ph = pk4fp8(hv[0], hv[1], hv[2], hv[3]);
    int o = (((lane >> 1) & 3) << 4) + (((lane >> 3) & 1) << 3) + ((lane & 1) << 2);
    uint8_t* base = A + (size_t)(n >> 7) * 65536 + (n & 127) * 64 + o;
    int ktx = lane >> 4;
    *(unsigned int*)(base + ktx * 8192) = px;
    *(unsigned int*)(base + (4 + ktx) * 8192) = ph;
  }

  // ---- logits
  float p[8];
#pragma unroll
  for (int j = 0; j < 8; ++j) p[j] = 0.0f;
#pragma unroll
  for (int ii = 0; ii < 4; ++ii) {
    int i = lane * 4 + ii;
    float xs = xv[ii], hs = hv[ii];
#pragma unroll
    for (int j = 0; j < 8; ++j)
      p[j] += xs * Wxz[i * 8 + j] + hs * Whz[i * 8 + j];
  }
#pragma unroll
  for (int j = 0; j < 8; ++j)
    for (int off = 32; off > 0; off >>= 1) p[j] += __shfl_down(p[j], off, 64);

  if (lane == 0) {
    int   iv = ((const int*)taup)[0];
    float fv = ((const float*)taup)[0];
    float tau = (iv >= 1 && iv < 100000) ? (float)iv : fv;
    float tinv = 1.0f / tau;

    float logit[8], e[8];
    float mx = -1e30f;
#pragma unroll
    for (int j = 0; j < 8; ++j) { logit[j] = p[j] + bxz[j]; mx = fmaxf(mx, logit[j]); }
    float s = 0.0f;
#pragma unroll
    for (int j = 0; j < 8; ++j) { e[j] = __expf(logit[j] - mx); s += e[j]; }
    float inv = 1.0f / s;
#pragma unroll
    for (int j = 0; j < 8; ++j) qz_out[(size_t)n * 8 + j] = e[j] * inv;

    float t[8];
    float mt = -1e30f;
#pragma unroll
    for (int j = 0; j < 8; ++j) {
      float uu = u[(size_t)n * 8 + j];
      float g = -__logf(-__logf(uu + 1e-10f) + 1e-10f);
      t[j] = (logit[j] + g) * tinv;
      mt = fmaxf(mt, t[j]);
    }
    float s2 = 0.0f;
#pragma unroll
    for (int j = 0; j < 8; ++j) { e[j] = __expf(t[j] - mt); s2 += e[j]; }
    float inv2 = 1.0f / s2;
#pragma unroll
    for (int j = 0; j < 8; ++j) z_out[(size_t)n * 8 + j] = e[j] * inv2;
  }
}

// ---------------- P2: Bt = [cb][kt][row][64B] fp8, col+K-permuted -----------------
// p(C) = (mm>>3)*256 + (g>>1)*128 + (g&1)*64 + (kk>>1)*16 + (kk&1)*8 + (mm&7)
__global__ void prep_Bt(const float* __restrict__ Wx, const float* __restrict__ Wh,
                        uint8_t* __restrict__ Bt) {
  __shared__ float tile[64][64];
  int tid = threadIdx.x;
  int wi = blockIdx.x & 7;            // 64-k window == kt
  int C0 = (blockIdx.x >> 3) << 6;    // 64-col group
#pragma unroll
  for (int qq = 0; qq < 16; ++qq) {
    int flat = qq * 256 + tid;
    int r = flat >> 6, c = flat & 63;
    int ig = wi * 64 + r;
    float v = (ig < 256) ? Wx[(size_t)ig * 8192 + C0 + c]
                         : Wh[(size_t)(ig - 256) * 8192 + C0 + c];
    tile[r][c] = v * 16.0f;
  }
  __syncthreads();
  int c = tid & 63, q = tid >> 6;
  int C = C0 + c;
  int g = C >> 11, kk = (C >> 8) & 7, mm = C & 255;
  int p = ((mm >> 3) << 8) | ((g >> 1) << 7) | ((g & 1) << 6)
        | ((kk >> 1) << 4) | ((kk & 1) << 3) | (mm & 7);
  uint4v o;
  o[0] = pk4fp8(tile[q * 8 + 0][c], tile[q * 8 + 1][c], tile[q * 8 + 2][c], tile[q * 8 + 3][c]);
  o[1] = pk4fp8(tile[q * 8 + 4][c], tile[q * 8 + 5][c], tile[q * 8 + 6][c], tile[q * 8 + 7][c]);
  o[2] = pk4fp8(tile[32 + q * 8 + 0][c], tile[32 + q * 8 + 1][c], tile[32 + q * 8 + 2][c], tile[32 + q * 8 + 3][c]);
  o[3] = pk4fp8(tile[32 + q * 8 + 4][c], tile[32 + q * 8 + 5][c], tile[32 + q * 8 + 6][c], tile[32 + q * 8 + 7][c]);
  *(uint4v*)(Bt + (size_t)(p >> 8) * 131072 + wi * 16384 + (p & 255) * 64 + q * 16) = o;
}

// ---------------- G: fp8 128x256-tile GEMM + fused LSTM epilogue ------------------
// 8 waves = 2M(wm) x 4N(wn). Per wave: 64 rows (wm*64 + j*16 + gl*4 + r),
// lane cols = the 4 gate-quadrants q of one (kk,mm): kk = wn*2+(ml>>3), mml = ml&7.
// acc[q][j] : q = gate (I,G,F,O), 16 float4v = 64 f32/lane.
__global__ __launch_bounds__(512, 4) void gates_kernel(
    const uint8_t* __restrict__ A,    // [rb 64][kt 8][128][64B] fp8
    const uint8_t* __restrict__ Bt,   // [cb 32][kt 8][256][64B] fp8
    const float* __restrict__ c0g,    // [8192][256]
    const float* __restrict__ bias,   // [8192]
    const float* __restrict__ zg,     // [8192][8]
    float* __restrict__ h_out, float* __restrict__ c_out) {
  __shared__ char smem[49152];  // A: 2 x 8KB @0 ; B: 2 x 16KB @16384

  const int tid = threadIdx.x;
  const int lane = tid & 63, ml = lane & 15, gl = lane >> 4;
  const int wid = tid >> 6, wm = wid >> 2, wn = wid & 3;

  // XCD-stripe: xcd owns rb {8x..8x+7}, cb outer / rb inner.
  const int xcd = blockIdx.x & 7;
  const int j_  = blockIdx.x >> 3;          // 0..255
  const int cb  = j_ >> 3;                  // 0..31
  const int rb  = (xcd << 3) | (j_ & 7);    // 0..63
  const int row0 = rb << 7;

  const uint8_t* Abp = A + (size_t)rb * 65536;
  const uint8_t* Bbp = Bt + (size_t)cb * 131072;

  // fragment LDS bases (contiguous 1KB per 16-row group: conflict-free)
  const char* pa = smem + (wm << 12) + ml * 64 + (gl << 4);            // + j*1024
  const char* pb = smem + 16384 + ((wn << 4) + ml) * 64 + (gl << 4);   // + q*4096

#define STGF(KTS) do { \
    const int kb_ = (KTS) & 1; \
    const uint8_t* sa_ = Abp + ((KTS) & 7) * 8192 + (tid << 4); \
    const uint8_t* sb_ = Bbp + ((KTS) & 7) * 16384 + (tid << 4); \
    gll16(sa_, smem + kb_ * 8192 + (tid << 4)); \
    gll16(sb_, smem + 16384 + kb_ * 16384 + (tid << 4)); \
    gll16(sb_ + 8192, smem + 16384 + kb_ * 16384 + 8192 + (tid << 4)); \
  } while (0)

#define RDAB(KB) { \
    _Pragma("unroll") for (int j = 0; j < 4; ++j) \
      af[j] = *(const llong2v*)(pa + (KB) * 8192 + j * 1024); \
    _Pragma("unroll") for (int q = 0; q < 4; ++q) \
      bf[q] = *(const llong2v*)(pb + (KB) * 16384 + q * 4096); }

#define MMALL() { _Pragma("unroll") for (int j = 0; j < 4; ++j) \
    _Pragma("unroll") for (int q = 0; q < 4; ++q) { \
      acc[q][j] = __builtin_amdgcn_mfma_f32_16x16x32_fp8_fp8(af[j][0], bf[q][0], acc[q][j], 0, 0, 0); \
      acc[q][j] = __builtin_amdgcn_mfma_f32_16x16x32_fp8_fp8(af[j][1], bf[q][1], acc[q][j], 0, 0, 0); } }

  float4v acc[4][4];   // [gate q][row frag j]
#pragma unroll
  for (int q = 0; q < 4; ++q)
#pragma unroll
    for (int j = 0; j < 4; ++j)
#pragma unroll
      for (int r = 0; r < 4; ++r) acc[q][j][r] = 0.0f;

  llong2v af[4], bf[4];

  // prologue: stage kt0 + kt1 (6 loads); wait own kt0 (3 left) ; barrier
  STGF(0); STGF(1);
  WAITVM3;
  BARRIER;

#pragma unroll
  for (int kt = 0; kt < 8; ++kt) {
    const int kb = kt & 1;

    RDAB(kb);                      // 8 x ds_read_b128
    WAITLGKM;
    PRIO1; MMALL(); PRIO0;         // 32 MFMA

    BARRIER;                       // all waves done reading slot kb
    if (kt <= 5) {
      STGF(kt + 2);                // overwrite slot kb with kt+2
      WAITVM3;                     // own kt+1 landed (kt+2's 3 outstanding)
      BARRIER;                     // all waves' kt+1 landed
    } else if (kt == 6) {
      WAITVM0;
      BARRIER;
    }
  }
#undef STGF
#undef RDAB
#undef MMALL

  // ---------------- fused LSTM epilogue ----------------
  const int kkl = (wn << 1) | (ml >> 3);
  const int mml = ml & 7;
  {
    const int mmg = (cb << 3) + mml;
    const float bI = bias[0 * 2048 + kkl * 256 + mmg];
    const float bG = bias[1 * 2048 + kkl * 256 + mmg];
    const float bF = bias[2 * 2048 + kkl * 256 + mmg];
    const float bO = bias[3 * 2048 + kkl * 256 + mmg];
    const float s16 = 0.0625f;   // undo W*16 pre-scale

    float hpart[4][4], cpart[4][4];
#pragma unroll
    for (int j = 0; j < 4; ++j) {
      const int nb = row0 + (wm << 6) + (j << 4) + (gl << 2);
#pragma unroll
      for (int r = 0; r < 4; ++r) {
        const int nrow = nb + r;
        float I = fmaf(acc[0][j][r], s16, bI);
        float G = fmaf(acc[1][j][r], s16, bG);
        float F = fmaf(acc[2][j][r], s16, bF);
        float O = fmaf(acc[3][j][r], s16, bO);
        float c0v = c0g[(size_t)nrow * 256 + mmg];
        float ct = fmaf(sigm(F), c0v, sigm(I) * tanh_(G));
        float ht = sigm(O) * tanh_(ct);
        float zv = zg[(size_t)nrow * 8 + kkl];
        float h1 = zv * ht, c1 = zv * ct;
        h1 += __shfl_xor(h1, 8, 64);    // combine the wave's kk pair
        c1 += __shfl_xor(c1, 8, 64);
        hpart[j][r] = h1;
        cpart[j][r] = c1;
      }
    }

    // pbuf [wn 4][row 128][16] : cols 0..7 = h, 8..15 = c  (32KB, reuses B region)
    float* pbuf = (float*)(smem + 16384);
    const bool wr = ((ml & 8) == 0);
    if (wr) {
#pragma unroll
      for (int j = 0; j < 4; ++j)
#pragma unroll
        for (int r = 0; r < 4; ++r) {
          int rloc = (wm << 6) + (j << 4) + (gl << 2) + r;
          pbuf[(wn << 11) + (rloc << 4) + mml]     = hpart[j][r];
          pbuf[(wn << 11) + (rloc << 4) + 8 + mml] = cpart[j][r];
        }
    }
    WAITLGKM; BARRIER;
    // reduce over wn and store: 1024 h then 1024 c, 512 threads x 2 each
#pragma unroll
    for (int i = 0; i < 2; ++i) {
      int idx = (i << 9) + tid;          // 0..1023
      int rloc = idx >> 3, mm2 = idx & 7;
      float hv = pbuf[(rloc << 4) + mm2]
               + pbuf[2048 + (rloc << 4) + mm2]
               + pbuf[4096 + (rloc << 4) + mm2]
               + pbuf[6144 + (rloc << 4) + mm2];
      float cv = pbuf[(rloc << 4) + 8 + mm2]
               + pbuf[2048 + (rloc << 4) + 8 + mm2]
               + pbuf[4096 + (rloc << 4) + 8 + mm2]
               + pbuf[6144 + (rloc << 4) + 8 + mm2];
      h_out[(size_t)(row0 + rloc) * 256 + (cb << 3) + mm2] = hv;
      c_out[(size_t)(row0 + rloc) * 256 + (cb << 3) + mm2] = cv;
    }
  }
}

extern "C" void kernel_launch(void* const* d_in, const int* in_sizes, int n_in,
                              void* d_out, int out_size, void* d_ws, size_t ws_size,
                              hipStream_t stream) {
  const float* x   = (const float*)d_in[0];
  const float* h0  = (const float*)d_in[1];
  const float* c0  = (const float*)d_in[2];
  const float* u   = (const float*)d_in[3];
  const float* Wxz = (const float*)d_in[4];
  const float* Whz = (const float*)d_in[5];
  const float* Wx4 = (const float*)d_in[6];
  const float* Wh4 = (const float*)d_in[7];
  const float* bxz = (const float*)d_in[8];
  const float* b4  = (const float*)d_in[9];
  const void*  tau = d_in[10];

  float* out    = (float*)d_out;
  float* z_out  = out;                       // [8192][8]
  float* qz_out = out + 65536;               // [8192][8]
  float* h_out  = out + 131072;              // [8192][256]
  float* c_out  = out + 131072 + 2097152;    // [8192][256]

  uint8_t* A  = (uint8_t*)d_ws;              // 4MB fp8
  uint8_t* Bt = A + 4194304;                 // 4MB fp8

  prep_logits<<<2048, 256, 0, stream>>>(x, h0, u, Wxz, Whz, bxz, tau, A, z_out, qz_out);
  prep_Bt<<<1024, 256, 0, stream>>>(Wx4, Wh4, Bt);
  gates_kernel<<<2048, 512, 0, stream>>>(A, Bt, c0, b4, z_out, h_out, c_out);
}

// Round 9
// 84.564 us; speedup vs baseline: 1.7953x; 1.0629x over previous
//
#include <hip/hip_runtime.h>
#include <stdint.h>

typedef float  float4v  __attribute__((ext_vector_type(4)));
typedef long long llong2v __attribute__((ext_vector_type(2)));
typedef unsigned int uint4v __attribute__((ext_vector_type(4)));

// Problem constants (N=8192, n_in=256, m=256, k=8)
// GEMM: [8192 x 512] x [512 x 8192] fp8 e4m3, fused LSTM epilogue.
// W pre-scaled by 16; acc scaled by 1/16 in epilogue.
// A  layout: [rb 64][kt 8][wm 2][j 4][gq 4][lane 16][16B]   (8KB per kt)
// Bt layout: [cb 32][kt 8][q 4][wn 4][gq 4][lane 16][16B]   (16KB per kt)
// Granule order gq*256 + lane*16 makes each quarter-wave's ds_read_b128 hit
// 16 CONTIGUOUS granules (256B burst, 2-way bank alias = free) instead of the
// old ml*64+gl*16 pattern (8-way conflict, 5.8e6 conflict cycles in R8).

__device__ __forceinline__ unsigned int pk4fp8(float a, float b, float c, float d) {
  unsigned int p = (unsigned int)__builtin_amdgcn_cvt_pk_fp8_f32(a, b, 0, false);
  p = (unsigned int)__builtin_amdgcn_cvt_pk_fp8_f32(c, d, (int)p, true);
  return p;
}

__device__ __forceinline__ float sigm(float x) {
  return __builtin_amdgcn_rcpf(1.0f + __expf(-x));
}
__device__ __forceinline__ float tanh_(float x) {
  return fmaf(2.0f, __builtin_amdgcn_rcpf(1.0f + __expf(-2.0f * x)), -1.0f);
}

__device__ __forceinline__ void gll16(const void* g, void* l) {
  __builtin_amdgcn_global_load_lds((const __attribute__((address_space(1))) void*)g,
                                   (__attribute__((address_space(3))) void*)l, 16, 0, 0);
}

#define BARRIER   asm volatile("s_barrier" ::: "memory")
#define WAITLGKM  asm volatile("s_waitcnt lgkmcnt(0)" ::: "memory")
#define WAITVM3   asm volatile("s_waitcnt vmcnt(3)" ::: "memory")
#define WAITVM0   asm volatile("s_waitcnt vmcnt(0)" ::: "memory")
#define PRIO1     __builtin_amdgcn_s_setprio(1)
#define PRIO0     __builtin_amdgcn_s_setprio(0)

// ------------- P1+L fused: A (fp8, conflict-free layout) + logits -----------------
__global__ void prep_logits(const float* __restrict__ x, const float* __restrict__ h,
                            const float* __restrict__ u, const float* __restrict__ Wxz,
                            const float* __restrict__ Whz, const float* __restrict__ bxz,
                            const void* __restrict__ taup,
                            uint8_t* __restrict__ A,
                            float* __restrict__ z_out, float* __restrict__ qz_out) {
  int lane = threadIdx.x & 63;
  int n = blockIdx.x * 4 + (threadIdx.x >> 6);
  float4v xv = *(const float4v*)(x + (size_t)n * 256 + lane * 4);
  float4v hv = *(const float4v*)(h + (size_t)n * 256 + lane * 4);

  // fp8 A write: lane i covers orig k = 4i..4i+3 (x) and 256+4i.. (h).
  // K-granule gq=(lane>>1)&3 holds k' in {8gq..8gq+7} (bytes 0-7) u {32+8gq..} (8-15).
  {
    unsigned int px = pk4fp8(xv[0], xv[1], xv[2], xv[3]);
    unsigned int ph = pk4fp8(hv[0], hv[1], hv[2], hv[3]);
    int r = n & 127;
    int gq  = (lane >> 1) & 3;
    int sub = ((lane >> 3) & 1) * 8 + (lane & 1) * 4;
    uint8_t* base = A + (size_t)(n >> 7) * 65536
                  + ((r >> 6) << 12) + (((r >> 4) & 3) << 10)
                  + (gq << 8) + ((r & 15) << 4) + sub;
    int ktx = lane >> 4;
    *(unsigned int*)(base + ktx * 8192) = px;
    *(unsigned int*)(base + (4 + ktx) * 8192) = ph;
  }

  // ---- logits
  float p[8];
#pragma unroll
  for (int j = 0; j < 8; ++j) p[j] = 0.0f;
#pragma unroll
  for (int ii = 0; ii < 4; ++ii) {
    int i = lane * 4 + ii;
    float xs = xv[ii], hs = hv[ii];
#pragma unroll
    for (int j = 0; j < 8; ++j)
      p[j] += xs * Wxz[i * 8 + j] + hs * Whz[i * 8 + j];
  }
#pragma unroll
  for (int j = 0; j < 8; ++j)
    for (int off = 32; off > 0; off >>= 1) p[j] += __shfl_down(p[j], off, 64);

  if (lane == 0) {
    int   iv = ((const int*)taup)[0];
    float fv = ((const float*)taup)[0];
    float tau = (iv >= 1 && iv < 100000) ? (float)iv : fv;
    float tinv = 1.0f / tau;

    float logit[8], e[8];
    float mx = -1e30f;
#pragma unroll
    for (int j = 0; j < 8; ++j) { logit[j] = p[j] + bxz[j]; mx = fmaxf(mx, logit[j]); }
    float s = 0.0f;
#pragma unroll
    for (int j = 0; j < 8; ++j) { e[j] = __expf(logit[j] - mx); s += e[j]; }
    float inv = 1.0f / s;
#pragma unroll
    for (int j = 0; j < 8; ++j) qz_out[(size_t)n * 8 + j] = e[j] * inv;

    float t[8];
    float mt = -1e30f;
#pragma unroll
    for (int j = 0; j < 8; ++j) {
      float uu = u[(size_t)n * 8 + j];
      float g = -__logf(-__logf(uu + 1e-10f) + 1e-10f);
      t[j] = (logit[j] + g) * tinv;
      mt = fmaxf(mt, t[j]);
    }
    float s2 = 0.0f;
#pragma unroll
    for (int j = 0; j < 8; ++j) { e[j] = __expf(t[j] - mt); s2 += e[j]; }
    float inv2 = 1.0f / s2;
#pragma unroll
    for (int j = 0; j < 8; ++j) z_out[(size_t)n * 8 + j] = e[j] * inv2;
  }
}

// ---------------- P2: Bt (fp8, conflict-free layout), col+K-permuted --------------
// p(C) = (mm>>3)*256 + (g>>1)*128 + (g&1)*64 + (kk>>1)*16 + (kk&1)*8 + (mm&7)
__global__ void prep_Bt(const float* __restrict__ Wx, const float* __restrict__ Wh,
                        uint8_t* __restrict__ Bt) {
  __shared__ float tile[64][64];
  int tid = threadIdx.x;
  int wi = blockIdx.x & 7;            // 64-k window == kt
  int C0 = (blockIdx.x >> 3) << 6;    // 64-col group
#pragma unroll
  for (int qq = 0; qq < 4; ++qq) {
    int flat = qq * 256 + tid;        // 1024 float4 = 64 x 64
    int rr = flat >> 4, c4 = (flat & 15) << 2;
    int ig = wi * 64 + rr;
    const float* src = (ig < 256) ? (Wx + (size_t)ig * 8192 + C0 + c4)
                                  : (Wh + (size_t)(ig - 256) * 8192 + C0 + c4);
    float4v v = *(const float4v*)src;
    float4v w;
#pragma unroll
    for (int e = 0; e < 4; ++e) w[e] = v[e] * 16.0f;
    *(float4v*)&tile[rr][c4] = w;
  }
  __syncthreads();
  int c = tid & 63, gq = tid >> 6;
  int C = C0 + c;
  int g = C >> 11, kk = (C >> 8) & 7, mm = C & 255;
  int p = ((mm >> 3) << 8) | ((g >> 1) << 7) | ((g & 1) << 6)
        | ((kk >> 1) << 4) | ((kk & 1) << 3) | (mm & 7);
  uint4v o;
  o[0] = pk4fp8(tile[gq * 8 + 0][c], tile[gq * 8 + 1][c], tile[gq * 8 + 2][c], tile[gq * 8 + 3][c]);
  o[1] = pk4fp8(tile[gq * 8 + 4][c], tile[gq * 8 + 5][c], tile[gq * 8 + 6][c], tile[gq * 8 + 7][c]);
  o[2] = pk4fp8(tile[32 + gq * 8 + 0][c], tile[32 + gq * 8 + 1][c], tile[32 + gq * 8 + 2][c], tile[32 + gq * 8 + 3][c]);
  o[3] = pk4fp8(tile[32 + gq * 8 + 4][c], tile[32 + gq * 8 + 5][c], tile[32 + gq * 8 + 6][c], tile[32 + gq * 8 + 7][c]);
  int cl = p & 255;   // q=cl>>6, wn=(cl>>4)&3, lane=cl&15
  int off = ((cl >> 6) << 12) + (((cl >> 4) & 3) << 10) + (gq << 8) + ((cl & 15) << 4);
  *(uint4v*)(Bt + (size_t)(p >> 8) * 131072 + wi * 16384 + off) = o;
}

// ---------------- G: fp8 128x256-tile GEMM + fused LSTM epilogue ------------------
// 8 waves = 2M(wm) x 4N(wn). Per wave: 64 rows (wm*64 + j*16 + gl*4 + r),
// lane cols = 4 gate-quadrants q of one (kk,mm): kk = wn*2+(ml>>3), mml = ml&7.
__global__ __launch_bounds__(512, 4) void gates_kernel(
    const uint8_t* __restrict__ A,    // [rb 64][kt 8][8KB] fp8
    const uint8_t* __restrict__ Bt,   // [cb 32][kt 8][16KB] fp8
    const float* __restrict__ c0g,    // [8192][256]
    const float* __restrict__ bias,   // [8192]
    const float* __restrict__ zg,     // [8192][8]
    float* __restrict__ h_out, float* __restrict__ c_out) {
  __shared__ char smem[49152];  // A: 2 x 8KB @0 ; B: 2 x 16KB @16384

  const int tid = threadIdx.x;
  const int lane = tid & 63, ml = lane & 15, gl = lane >> 4;
  const int wid = tid >> 6, wm = wid >> 2, wn = wid & 3;

  // XCD-stripe: xcd owns rb {8x..8x+7}, cb outer / rb inner.
  const int xcd = blockIdx.x & 7;
  const int j_  = blockIdx.x >> 3;          // 0..255
  const int cb  = j_ >> 3;                  // 0..31
  const int rb  = (xcd << 3) | (j_ & 7);    // 0..63
  const int row0 = rb << 7;

  const uint8_t* Abp = A + (size_t)rb * 65536;
  const uint8_t* Bbp = Bt + (size_t)cb * 131072;

  // fragment LDS bases — quarter-wave-contiguous (gq*256 + ml*16)
  const char* pa = smem + (wm << 12) + (gl << 8) + (ml << 4);            // + j*1024
  const char* pb = smem + 16384 + (wn << 10) + (gl << 8) + (ml << 4);    // + q*4096

#define STGF(KTS) do { \
    const int kb_ = (KTS) & 1; \
    const uint8_t* sa_ = Abp + ((KTS) & 7) * 8192 + (tid << 4); \
    const uint8_t* sb_ = Bbp + ((KTS) & 7) * 16384 + (tid << 4); \
    gll16(sa_, smem + kb_ * 8192 + (tid << 4)); \
    gll16(sb_, smem + 16384 + kb_ * 16384 + (tid << 4)); \
    gll16(sb_ + 8192, smem + 16384 + kb_ * 16384 + 8192 + (tid << 4)); \
  } while (0)

#define RDAB(KB) { \
    _Pragma("unroll") for (int j = 0; j < 4; ++j) \
      af[j] = *(const llong2v*)(pa + (KB) * 8192 + j * 1024); \
    _Pragma("unroll") for (int q = 0; q < 4; ++q) \
      bf[q] = *(const llong2v*)(pb + (KB) * 16384 + q * 4096); }

#define MMALL() { _Pragma("unroll") for (int j = 0; j < 4; ++j) \
    _Pragma("unroll") for (int q = 0; q < 4; ++q) { \
      acc[q][j] = __builtin_amdgcn_mfma_f32_16x16x32_fp8_fp8(af[j][0], bf[q][0], acc[q][j], 0, 0, 0); \
      acc[q][j] = __builtin_amdgcn_mfma_f32_16x16x32_fp8_fp8(af[j][1], bf[q][1], acc[q][j], 0, 0, 0); } }

  float4v acc[4][4];   // [gate q][row frag j]
#pragma unroll
  for (int q = 0; q < 4; ++q)
#pragma unroll
    for (int j = 0; j < 4; ++j)
#pragma unroll
      for (int r = 0; r < 4; ++r) acc[q][j][r] = 0.0f;

  llong2v af[4], bf[4];

  // prologue: stage kt0 + kt1 (6 loads); wait own kt0 (3 left) ; barrier
  STGF(0); STGF(1);
  WAITVM3;
  BARRIER;

#pragma unroll
  for (int kt = 0; kt < 8; ++kt) {
    const int kb = kt & 1;

    RDAB(kb);                      // 8 x ds_read_b128, conflict-free
    WAITLGKM;
    PRIO1; MMALL(); PRIO0;         // 32 MFMA

    BARRIER;                       // all waves done reading slot kb
    if (kt <= 5) {
      STGF(kt + 2);                // overwrite slot kb with kt+2
      WAITVM3;                     // own kt+1 landed (kt+2's 3 outstanding)
      BARRIER;                     // all waves' kt+1 landed
    } else if (kt == 6) {
      WAITVM0;
      BARRIER;
    }
  }
#undef STGF
#undef RDAB
#undef MMALL

  // ---------------- fused LSTM epilogue ----------------
  const int kkl = (wn << 1) | (ml >> 3);
  const int mml = ml & 7;
  {
    const int mmg = (cb << 3) + mml;
    const float bI = bias[0 * 2048 + kkl * 256 + mmg];
    const float bG = bias[1 * 2048 + kkl * 256 + mmg];
    const float bF = bias[2 * 2048 + kkl * 256 + mmg];
    const float bO = bias[3 * 2048 + kkl * 256 + mmg];
    const float s16 = 0.0625f;   // undo W*16 pre-scale

    float hpart[4][4], cpart[4][4];
#pragma unroll
    for (int j = 0; j < 4; ++j) {
      const int nb = row0 + (wm << 6) + (j << 4) + (gl << 2);
#pragma unroll
      for (int r = 0; r < 4; ++r) {
        const int nrow = nb + r;
        float I = fmaf(acc[0][j][r], s16, bI);
        float G = fmaf(acc[1][j][r], s16, bG);
        float F = fmaf(acc[2][j][r], s16, bF);
        float O = fmaf(acc[3][j][r], s16, bO);
        float c0v = c0g[(size_t)nrow * 256 + mmg];
        float ct = fmaf(sigm(F), c0v, sigm(I) * tanh_(G));
        float ht = sigm(O) * tanh_(ct);
        float zv = zg[(size_t)nrow * 8 + kkl];
        float h1 = zv * ht, c1 = zv * ct;
        h1 += __shfl_xor(h1, 8, 64);    // combine the wave's kk pair
        c1 += __shfl_xor(c1, 8, 64);
        hpart[j][r] = h1;
        cpart[j][r] = c1;
      }
    }

    // pbuf [wn 4][row 128][16] : cols 0..7 = h, 8..15 = c  (32KB, reuses B region)
    float* pbuf = (float*)(smem + 16384);
    const bool wr = ((ml & 8) == 0);
    if (wr) {
#pragma unroll
      for (int j = 0; j < 4; ++j)
#pragma unroll
        for (int r = 0; r < 4; ++r) {
          int rloc = (wm << 6) + (j << 4) + (gl << 2) + r;
          pbuf[(wn << 11) + (rloc << 4) + mml]     = hpart[j][r];
          pbuf[(wn << 11) + (rloc << 4) + 8 + mml] = cpart[j][r];
        }
    }
    WAITLGKM; BARRIER;
    // reduce over wn and store: 1024 h then 1024 c, 512 threads x 2 each
#pragma unroll
    for (int i = 0; i < 2; ++i) {
      int idx = (i << 9) + tid;          // 0..1023
      int rloc = idx >> 3, mm2 = idx & 7;
      float hv = pbuf[(rloc << 4) + mm2]
               + pbuf[2048 + (rloc << 4) + mm2]
               + pbuf[4096 + (rloc << 4) + mm2]
               + pbuf[6144 + (rloc << 4) + mm2];
      float cv = pbuf[(rloc << 4) + 8 + mm2]
               + pbuf[2048 + (rloc << 4) + 8 + mm2]
               + pbuf[4096 + (rloc << 4) + 8 + mm2]
               + pbuf[6144 + (rloc << 4) + 8 + mm2];
      h_out[(size_t)(row0 + rloc) * 256 + (cb << 3) + mm2] = hv;
      c_out[(size_t)(row0 + rloc) * 256 + (cb << 3) + mm2] = cv;
    }
  }
}

extern "C" void kernel_launch(void* const* d_in, const int* in_sizes, int n_in,
                              void* d_out, int out_size, void* d_ws, size_t ws_size,
                              hipStream_t stream) {
  const float* x   = (const float*)d_in[0];
  const float* h0  = (const float*)d_in[1];
  const float* c0  = (const float*)d_in[2];
  const float* u   = (const float*)d_in[3];
  const float* Wxz = (const float*)d_in[4];
  const float* Whz = (const float*)d_in[5];
  const float* Wx4 = (const float*)d_in[6];
  const float* Wh4 = (const float*)d_in[7];
  const float* bxz = (const float*)d_in[8];
  const float* b4  = (const float*)d_in[9];
  const void*  tau = d_in[10];

  float* out    = (float*)d_out;
  float* z_out  = out;                       // [8192][8]
  float* qz_out = out + 65536;               // [8192][8]
  float* h_out  = out + 131072;              // [8192][256]
  float* c_out  = out + 131072 + 2097152;    // [8192][256]

  uint8_t* A  = (uint8_t*)d_ws;              // 4MB fp8
  uint8_t* Bt = A + 4194304;                 // 4MB fp8

  prep_logits<<<2048, 256, 0, stream>>>(x, h0, u, Wxz, Whz, bxz, tau, A, z_out, qz_out);
  prep_Bt<<<1024, 256, 0, stream>>>(Wx4, Wh4, Bt);
  gates_kernel<<<2048, 512, 0, stream>>>(A, Bt, c0, b4, z_out, h_out, c_out);
}